// Round 2
// baseline (371.841 us; speedup 1.0000x reference)
//
#include <hip/hip_runtime.h>
#include <hip/hip_bf16.h>

// TransformerEncoderLayer: B=4,S=4096,D=1024, 8 heads x 128.
//   cast x -> bf16; transpose+cast W* -> Wt[n][k] bf16 (one merged kernel)
//   GEMM1: qkv = x @ [Wq|Wk|Wv] + b      (bf16 out)
//   attention: per-token 8x8 softmax     (1 wave/token; attn_w -> d_out tail)
//   GEMM2: h = relu(out @ W1 + b1)       (bf16 out)
//   GEMM3: ff = h @ W2 + b2              (fp32 -> d_out head)
//
// R7: fix R6's serialized 8-phase schedule with COUNTED lgkm waits
// (HK derived-waits). R6 did [reads][barrier][lgkmcnt(0)][MFMA][barrier]:
// LDS drain and MFMA issue serialized globally -> 877 TF, MfmaUtil 36%.
// Now each phase prefetches the NEXT quadrant's registers BEFORE its own
// MFMA burst and waits lgkmcnt(R_p) (own prefetch floats across the burst):
//   phase: [vmcnt gate p3/p7][barrier][ds_reads next-quadrant][STG 1 unit]
//          [lgkmcnt(R_p)+sched_barrier][setprio(1) 16 MFMA setprio(0)]
// Quadrant order Q1=aL*bL Q2=aL*bH Q3=aH*bL Q4=aH*bH; prefetch targets
// (bH, aH, aL', bL') never collide with the current burst's operands ->
// no extra VGPRs. Reads/phase = 4/8/8/4. One barrier per phase (8/iter).
// Stage ledger (1 unit/phase): p1..p4 stage tile E'(buf0) {Alo,Blo,Bhi,Ahi},
// p5..p8 stage tile O'(buf1) same; each unit's region had its last ds_read
// complete >=1 full phase earlier (verified per-region). vmcnt(4) gates at
// p3 (tile O landed) and p7 (tile E' landed): outstanding=12 loads, oldest
// 8 = the gated tile. Tail: kt clamped (redundant L2-hot loads), uniform
// loop (#pragma unroll 1) keeps the hand-counted waits valid.

#define DI __device__ __forceinline__

typedef __bf16 bf16raw;
typedef bf16raw bf16x8 __attribute__((ext_vector_type(8)));
typedef float floatx4 __attribute__((ext_vector_type(4)));

DI unsigned short f2bf(float f) {
    __hip_bfloat16 h = __float2bfloat16(f);  // RNE
    return *reinterpret_cast<unsigned short*>(&h);
}

// async global->LDS, 16B per lane; LDS dest is wave-uniform base + lane*16
DI void async16(unsigned short* lds, const unsigned short* g) {
    __builtin_amdgcn_global_load_lds(
        (const __attribute__((address_space(1))) void*)g,
        (__attribute__((address_space(3))) void*)lds,
        16, 0, 0);
}

template <typename T> DI T cvt_out(float v);
template <> DI float cvt_out<float>(float v) { return v; }
template <> DI unsigned short cvt_out<unsigned short>(float v) { return f2bf(v); }

// 16 MFMAs: one quadrant (4 row-frags x 2 col-frags) x K=64 (2 k-steps).
template <int I0, int J0>
DI void mfma16(floatx4 (&acc)[8][4], const bf16x8 (&af)[4][2],
               const bf16x8 (&bf)[2][2]) {
#pragma unroll
    for (int s = 0; s < 2; s++)
#pragma unroll
        for (int i = 0; i < 4; i++)
#pragma unroll
            for (int j = 0; j < 2; j++)
                acc[I0 + i][J0 + j] = __builtin_amdgcn_mfma_f32_16x16x32_bf16(
                    af[i][s], bf[j][s], acc[I0 + i][J0 + j], 0, 0, 0);
}

// Stage one 128-row unit (2 x global_load_lds dwordx4; wave w covers 8 rows
// per issue).  rb = 0 (lo unit) or 128 (hi unit).
#define STG_A(b, rb, kt) do { \
    async16(&As[b][(rb) * 64 + wofs], aS + (size_t)(rb) * K + (kt)); \
    async16(&As[b][((rb) + 64) * 64 + wofs], aS + (size_t)((rb) + 64) * K + (kt)); \
} while (0)
#define STG_B(b, rb, kt) do { \
    async16(&Bs[b][(rb) * 64 + wofs], bS + (size_t)(rb) * K + (kt)); \
    async16(&Bs[b][((rb) + 64) * 64 + wofs], bS + (size_t)((rb) + 64) * K + (kt)); \
} while (0)
// 4 row-frags x 2 k-steps (8 x ds_read_b128)
#define LDA4(dst, b, base) do { _Pragma("unroll") \
    for (int i_ = 0; i_ < 4; i_++) { \
        dst[i_][0] = *reinterpret_cast<const bf16x8*>(&As[b][(base) + i_ * 1024 + sl0]); \
        dst[i_][1] = *reinterpret_cast<const bf16x8*>(&As[b][(base) + i_ * 1024 + sl1]); \
    } } while (0)
// 2 col-frags x 2 k-steps (4 x ds_read_b128)
#define LDB4(dst, b, base) do { _Pragma("unroll") \
    for (int j_ = 0; j_ < 2; j_++) { \
        dst[j_][0] = *reinterpret_cast<const bf16x8*>(&Bs[b][(base) + j_ * 1024 + sl0]); \
        dst[j_][1] = *reinterpret_cast<const bf16x8*>(&Bs[b][(base) + j_ * 1024 + sl1]); \
    } } while (0)
#define BARRIER __builtin_amdgcn_s_barrier()
#define LGKM(n) do { asm volatile("s_waitcnt lgkmcnt(" #n ")" ::: "memory"); \
    __builtin_amdgcn_sched_barrier(0); } while (0)
#define GATE4 asm volatile("s_waitcnt vmcnt(4)" ::: "memory")
#define PRIO1 __builtin_amdgcn_s_setprio(1)
#define PRIO0 __builtin_amdgcn_s_setprio(0)

// ---------------------------------------------------------------------------
// C[M][N] = A[M][K] @ B[K][N] + bias, Bt = B^T given as [N][K] bf16.
// ---------------------------------------------------------------------------
template <int K, int N, int GX, typename OutT, bool RELU>
__global__ __launch_bounds__(512, 2)
void gemm256_bt(const unsigned short* __restrict__ A,   // [M][K] bf16
                const unsigned short* __restrict__ Bt,  // [N][K] bf16
                const float* __restrict__ bias,         // [N]
                OutT* __restrict__ C)                   // [M][N]
{
    constexpr int BK = 64;
    constexpr int NT = K / BK;      // 16 K-tiles
    constexpr int NP = NT / 2;      // 8 pair-iterations
    static_assert(NT % 2 == 0 && N % 256 == 0, "");

    __shared__ unsigned short As[2][256 * BK];   // 2 x 32 KB
    __shared__ unsigned short Bs[2][256 * BK];   // 2 x 32 KB

    const int tid  = threadIdx.x;
    const int wave = tid >> 6;
    const int lane = tid & 63;
    const int quad = lane >> 4;
    const int l16  = lane & 15;
    const int sw7  = l16 & 7;
    const int wm   = wave >> 2;     // 0..1 (M half)
    const int wn   = wave & 3;      // 0..3 (N quarter)

    // XCD swizzle (grids are multiples of 8 blocks)
    const int g   = blockIdx.x + GX * blockIdx.y;
    const int xcd = g & 7;
    const int t   = g >> 3;
    const int bx  = t % GX;
    const int by  = t / GX + (gridDim.y >> 3) * xcd;
    const int m0  = by * 256;
    const int n0  = bx * 256;

    // staging source: thread tid covers row (tid>>3) of a 64-row issue,
    // phys oct (tid&7) holds logical oct (tid&7)^(row&7)  (R4 swizzle)
    const int srow = tid >> 3;
    const int soct = ((tid & 7) ^ (srow & 7)) * 8;
    const unsigned short* aS = A  + (size_t)(m0 + srow) * K + soct;
    const unsigned short* bS = Bt + (size_t)(n0 + srow) * K + soct;
    const int wofs = wave * 512;    // wave's 8-row slice within an issue

    // frag-read bases (shorts): logical oct o of row r lives at o^(r&7)
    const int aro = (wm * 64 + l16) * 64;
    const int bro = (wn * 32 + l16) * 64;
    const int sl0 = (quad ^ sw7) * 8;
    const int sl1 = ((quad + 4) ^ sw7) * 8;

    floatx4 acc[8][4];
    const floatx4 zero = {0.f, 0.f, 0.f, 0.f};
#pragma unroll
    for (int i = 0; i < 8; i++)
#pragma unroll
        for (int j = 0; j < 4; j++) acc[i][j] = zero;

    bf16x8 aL[4][2], aH[4][2], bL[2][2], bH[2][2];

    // Prologue: tile0 -> buf0, tile1 -> buf1 (16 loads); wait tile0 only
    // (tile1's 8 float); read aL,bL of tile0 and drain them once.
    STG_A(0, 0, 0); STG_B(0, 0, 0); STG_B(0, 128, 0); STG_A(0, 128, 0);
    STG_A(1, 0, BK); STG_B(1, 0, BK); STG_B(1, 128, BK); STG_A(1, 128, BK);
    asm volatile("s_waitcnt vmcnt(8)" ::: "memory");
    BARRIER;
    LDA4(aL, 0, aro);
    LDB4(bL, 0, bro);
    asm volatile("s_waitcnt lgkmcnt(0)" ::: "memory");
    __builtin_amdgcn_sched_barrier(0);

#pragma unroll 1
    for (int it = 0; it < NP; ++it) {
        // tiles: E=2it (buf0), O=2it+1 (buf1); prefetch E'=2it+2, O'=2it+3
        const int kt2 = ((2 * it + 2) < NT ? (2 * it + 2) : (NT - 1)) * BK;
        const int kt3 = ((2 * it + 3) < NT ? (2 * it + 3) : (NT - 1)) * BK;

        // p1: MFMA Q1(E)=aL*bL | prefetch bH(E) | stage Alo(E')->buf0
        BARRIER;
        LDB4(bH, 0, bro + 8192);
        STG_A(0, 0, kt2);
        LGKM(4);
        PRIO1; mfma16<0, 0>(acc, aL, bL); PRIO0;

        // p2: MFMA Q2(E)=aL*bH | prefetch aH(E) | stage Blo(E')
        BARRIER;
        LDA4(aH, 0, aro + 8192);
        STG_B(0, 0, kt2);
        LGKM(8);
        PRIO1; mfma16<0, 2>(acc, aL, bH); PRIO0;

        // p3: gate tile O landed | MFMA Q3(E)=aH*bL | prefetch aL(O) | Bhi(E')
        GATE4;
        BARRIER;
        LDA4(aL, 1, aro);
        STG_B(0, 128, kt2);
        LGKM(8);
        PRIO1; mfma16<4, 0>(acc, aH, bL); PRIO0;

        // p4: MFMA Q4(E)=aH*bH | prefetch bL(O) | stage Ahi(E')
        BARRIER;
        LDB4(bL, 1, bro);
        STG_A(0, 128, kt2);
        LGKM(4);
        PRIO1; mfma16<4, 2>(acc, aH, bH); PRIO0;

        // p5: MFMA Q1(O)=aL*bL | prefetch bH(O) | stage Alo(O')->buf1
        BARRIER;
        LDB4(bH, 1, bro + 8192);
        STG_A(1, 0, kt3);
        LGKM(4);
        PRIO1; mfma16<0, 0>(acc, aL, bL); PRIO0;

        // p6: MFMA Q2(O)=aL*bH | prefetch aH(O) | stage Blo(O')
        BARRIER;
        LDA4(aH, 1, aro + 8192);
        STG_B(1, 0, kt3);
        LGKM(8);
        PRIO1; mfma16<0, 2>(acc, aL, bH); PRIO0;

        // p7: gate tile E' landed | MFMA Q3(O)=aH*bL | prefetch aL(E') | Bhi(O')
        GATE4;
        BARRIER;
        LDA4(aL, 0, aro);
        STG_B(1, 128, kt3);
        LGKM(8);
        PRIO1; mfma16<4, 0>(acc, aH, bL); PRIO0;

        // p8: MFMA Q4(O)=aH*bH | prefetch bL(E') | stage Ahi(O')
        BARRIER;
        LDB4(bL, 0, bro);
        STG_A(1, 128, kt3);
        LGKM(4);
        PRIO1; mfma16<4, 2>(acc, aH, bH); PRIO0;
    }
    // drain leftover (clamped-tail) loads before epilogue/exit
    asm volatile("s_waitcnt vmcnt(0)" ::: "memory");

    // Epilogue (16x16x32 D layout: row = quad*4 + r, col = l16)
#pragma unroll
    for (int j = 0; j < 4; j++) {
        const int col = n0 + wn * 32 + (j & 1) * 16 + (j >> 1) * 128 + l16;
        const float bv = bias[col];
#pragma unroll
        for (int i = 0; i < 8; i++) {
            const int rb = m0 + wm * 64 + (i & 3) * 16 + (i >> 2) * 128 + quad * 4;
#pragma unroll
            for (int r = 0; r < 4; r++) {
                float v = acc[i][j][r] + bv;
                if (RELU) v = fmaxf(v, 0.f);
                C[(size_t)(rb + r) * N + col] = cvt_out<OutT>(v);
            }
        }
    }
}

#undef STG_A
#undef STG_B
#undef LDA4
#undef LDB4
#undef BARRIER
#undef LGKM
#undef GATE4
#undef PRIO1
#undef PRIO0

// ---------------------------------------------------------------------------
// cast fp32 -> bf16, 4 elems/thread
__global__ void cast_f32_to_bf16(const float* __restrict__ src,
                                 unsigned short* __restrict__ dst, int n4) {
    int i = blockIdx.x * blockDim.x + threadIdx.x;
    if (i < n4) {
        float4 v = reinterpret_cast<const float4*>(src)[i];
        ushort4 o = { f2bf(v.x), f2bf(v.y), f2bf(v.z), f2bf(v.w) };
        reinterpret_cast<ushort4*>(dst)[i] = o;
    }
}

// 5x W[k][n] fp32 (1024x1024) -> Wt[n][k] bf16, z-indexed
struct WPack {
    const float* src[5];
    unsigned short* dst[5];
};
__global__ void transpose_cast_all(WPack p) {
    __shared__ float tile[32][33];
    const float* W = p.src[blockIdx.z];
    unsigned short* Wt = p.dst[blockIdx.z];
    const int n0 = blockIdx.x * 32, k0 = blockIdx.y * 32;
    const int tx = threadIdx.x, ty = threadIdx.y;  // 32 x 8
#pragma unroll
    for (int i = 0; i < 32; i += 8)
        tile[ty + i][tx] = W[(size_t)(k0 + ty + i) * 1024 + n0 + tx];
    __syncthreads();
#pragma unroll
    for (int i = 0; i < 32; i += 8)
        Wt[(size_t)(n0 + ty + i) * 1024 + k0 + tx] = f2bf(tile[tx][ty + i]);
}

__global__ void concat_bias(const float* __restrict__ bq,
                            const float* __restrict__ bk,
                            const float* __restrict__ bv,
                            float* __restrict__ dst) {
    int i = blockIdx.x * blockDim.x + threadIdx.x;  // 3072
    const float* s = (i < 1024) ? bq : ((i < 2048) ? bk : bv);
    dst[i] = s[i & 1023];
}

// ---------------------------------------------------------------------------
// Per-token attention over 8 heads. qkv row: [q(1024)|k(1024)|v(1024)] bf16.
// 4 tokens per block, ONE WAVE PER TOKEN. bf16 stays bf16 in LDS.
DI float dot8(unsigned a, unsigned b, float acc) {
    union { unsigned u; float f; } al, ah, bl, bh;
    al.u = a << 16; ah.u = a & 0xffff0000u;
    bl.u = b << 16; bh.u = b & 0xffff0000u;
    return acc + al.f * bl.f + ah.f * bh.f;
}

__global__ __launch_bounds__(256)
void attention_kernel(const unsigned short* __restrict__ qkv,  // [M][3072]
                      unsigned short* __restrict__ out_bf,     // [M][1024]
                      float* __restrict__ attn_w)              // [M][64]
{
    __shared__ unsigned short sqkv[4][3072];   // 24 KB
    __shared__ float sw[4][64];
    const int tid  = threadIdx.x;
    const int wave = tid >> 6;
    const int lane = tid & 63;
    const int m    = blockIdx.x * 4 + wave;    // this wave's token

    // Stage own token's qkv row: 384 uint4 chunks / 64 lanes = 6 per lane
    {
        const uint4* src = reinterpret_cast<const uint4*>(qkv + (size_t)m * 3072);
        uint4* dst = reinterpret_cast<uint4*>(&sqkv[wave][0]);
#pragma unroll
        for (int i = 0; i < 6; i++) dst[lane + 64 * i] = src[lane + 64 * i];
    }
    __syncthreads();

    // QK + softmax: lane = h*8 + t
    {
        const int h = lane >> 3, t = lane & 7;
        const uint2* q8 = reinterpret_cast<const uint2*>(&sqkv[wave][h * 128]);
        const uint2* k8 = reinterpret_cast<const uint2*>(&sqkv[wave][1024 + t * 128]);
        float dot = 0.f;
#pragma unroll
        for (int d = 0; d < 32; d++) {
            uint2 a = q8[d], b = k8[d];
            dot = dot8(a.x, b.x, dot);
            dot = dot8(a.y, b.y, dot);
        }
        float score = dot * 0.08838834764831843f;  // 1/sqrt(128)
        float mx = score;
#pragma unroll
        for (int o = 1; o < 8; o <<= 1) mx = fmaxf(mx, __shfl_xor(mx, o, 8));
        float e = __expf(score - mx);
        float sum = e;
#pragma unroll
        for (int o = 1; o < 8; o <<= 1) sum += __shfl_xor(sum, o, 8);
        float w = e / sum;
        sw[wave][lane] = w;
        attn_w[(size_t)m * 64 + lane] = w;     // [m][h][t], coalesced per wave
    }
    __syncthreads();

    // PV: lane owns output cols [lane*16, lane*16+16) = head h = lane>>3,
    // within-head dims d0..d0+15 with d0 = (lane&7)*16.  v is [t][d].
    {
        const int h  = lane >> 3;
        const int d0 = (lane & 7) * 16;        // within-head dim
        float acc[16];
#pragma unroll
        for (int i = 0; i < 16; i++) acc[i] = 0.f;
#pragma unroll
        for (int t = 0; t < 8; t++) {
            const float w = sw[wave][h * 8 + t];
            const uint4* v8 = reinterpret_cast<const uint4*>(
                &sqkv[wave][2048 + t * 128 + d0]);
            uint4 v0 = v8[0], v1 = v8[1];
            unsigned vv[8] = { v0.x, v0.y, v0.z, v0.w, v1.x, v1.y, v1.z, v1.w };
#pragma unroll
            for (int i = 0; i < 8; i++) {
                union { unsigned u; float f; } lo, hi;
                lo.u = vv[i] << 16; hi.u = vv[i] & 0xffff0000u;
                acc[i * 2]     += w * lo.f;
                acc[i * 2 + 1] += w * hi.f;
            }
        }
        unsigned o[8];
#pragma unroll
        for (int i = 0; i < 8; i++)
            o[i] = (unsigned)f2bf(acc[i * 2]) | ((unsigned)f2bf(acc[i * 2 + 1]) << 16);
        uint4* dst = reinterpret_cast<uint4*>(out_bf + (size_t)m * 1024 + lane * 16);
        dst[0] = make_uint4(o[0], o[1], o[2], o[3]);
        dst[1] = make_uint4(o[4], o[5], o[6], o[7]);
    }
}

// ---------------------------------------------------------------------------
extern "C" void kernel_launch(void* const* d_in, const int* in_sizes, int n_in,
                              void* d_out, int out_size, void* d_ws, size_t ws_size,
                              hipStream_t stream) {
    const float* x  = (const float*)d_in[0];
    const float* Wq = (const float*)d_in[1];
    const float* bq = (const float*)d_in[2];
    const float* Wk = (const float*)d_in[3];
    const float* bk = (const float*)d_in[4];
    const float* Wv = (const float*)d_in[5];
    const float* bv = (const float*)d_in[6];
    const float* W1 = (const float*)d_in[7];
    const float* b1 = (const float*)d_in[8];
    const float* W2 = (const float*)d_in[9];
    const float* b2 = (const float*)d_in[10];

    constexpr int D = 1024;
    constexpr int M = 4 * 4096;              // 16384 tokens
    constexpr size_t XN = (size_t)M * D;

    float* ff_out   = (float*)d_out;         // [M][1024]
    float* attn_out = (float*)d_out + XN;    // [M][64]

    char* ws = (char*)d_ws;
    size_t off = 0;
    auto alloc = [&](size_t bytes) -> char* {
        char* p = ws + off;
        off += (bytes + 255) & ~(size_t)255;
        return p;
    };
    unsigned short* Xbf   = (unsigned short*)alloc(XN * 2);
    unsigned short* Wtqkv = (unsigned short*)alloc((size_t)3 * D * D * 2);
    unsigned short* Wt1   = (unsigned short*)alloc((size_t)D * D * 2);
    unsigned short* Wt2   = (unsigned short*)alloc((size_t)D * D * 2);
    float*          bqkv  = (float*)alloc(3 * D * 4);
    unsigned short* outbf = (unsigned short*)alloc(XN * 2);
    unsigned short* hbf   = (unsigned short*)alloc(XN * 2);
    unsigned short* qkv   = (unsigned short*)alloc((size_t)M * 3 * D * 2);

    // prep
    cast_f32_to_bf16<<<(int)(XN / 4 / 256), 256, 0, stream>>>(x, Xbf, (int)(XN / 4));
    WPack p;
    p.src[0] = Wq; p.dst[0] = Wtqkv;
    p.src[1] = Wk; p.dst[1] = Wtqkv + (size_t)D * D;
    p.src[2] = Wv; p.dst[2] = Wtqkv + (size_t)2 * D * D;
    p.src[3] = W1; p.dst[3] = Wt1;
    p.src[4] = W2; p.dst[4] = Wt2;
    transpose_cast_all<<<dim3(32, 32, 5), dim3(32, 8), 0, stream>>>(p);
    concat_bias<<<12, 256, 0, stream>>>(bq, bk, bv, bqkv);

    // QKV projection + attention
    gemm256_bt<D, 3 * D, 12, unsigned short, false>
        <<<dim3(12, 64), 512, 0, stream>>>(Xbf, Wtqkv, bqkv, qkv);
    attention_kernel<<<M / 4, 256, 0, stream>>>(qkv, outbf, attn_out);

    // FFN
    gemm256_bt<D, D, 4, unsigned short, true>
        <<<dim3(4, 64), 512, 0, stream>>>(outbf, Wt1, b1, hbf);
    gemm256_bt<D, D, 4, float, false>
        <<<dim3(4, 64), 512, 0, stream>>>(hbf, Wt2, b2, ff_out);
}

// Round 4
// 364.214 us; speedup vs baseline: 1.0209x; 1.0209x over previous
//
#include <hip/hip_runtime.h>
#include <hip/hip_bf16.h>

// TransformerEncoderLayer: B=4,S=4096,D=1024, 8 heads x 128.
//   cast x -> bf16; transpose+cast W* -> Wt[n][k] bf16 (one merged kernel)
//   GEMM1: qkv = x @ [Wq|Wk|Wv] + b      (bf16 out)
//   attention: per-token 8x8 softmax     (1 wave/token; attn_w -> d_out tail)
//   GEMM2: h = relu(out @ W1 + b1)       (bf16 out)
//   GEMM3: ff = h @ W2 + b2              (fp32 -> d_out head)
//
// R9 = R8 hardened: same 8-phase schedule with COUNTED lgkm waits and
// inline-asm ds_read_b128 (opaque to compiler waitcnt insertion), but asm
// operands are uint32x4 (bit-cast to bf16x8 only at the MFMA call) --
// __bf16-vector asm constraints are the one fragile piece of R8 and the
// prime suspect for the round-3 container failure.
//   phase: [gate vmcnt(4) @p3/p7][barrier][asm ds_reads next-quadrant]
//          [STG 1 unit][lgkmcnt(4 or 8)+sched_barrier][16 MFMA]
// Ledger (re-audited): reads/phase 4/8/8/4; each phase's counted lgkm wait
// drains exactly the quadrant its MFMA burst consumes, leaving its own
// prefetch floating; vmcnt(4) gates at p3 (tile O) / p7 (tile E') precede
// the barrier so all waves' stage loads have landed; every staged region's
// floating readers are drained one full phase + barrier before overwrite.

#define DI __device__ __forceinline__

typedef __bf16 bf16raw;
typedef bf16raw bf16x8 __attribute__((ext_vector_type(8)));
typedef float floatx4 __attribute__((ext_vector_type(4)));
typedef unsigned int uint32x4 __attribute__((ext_vector_type(4)));

DI unsigned short f2bf(float f) {
    __hip_bfloat16 h = __float2bfloat16(f);  // RNE
    return *reinterpret_cast<unsigned short*>(&h);
}

// async global->LDS, 16B per lane; LDS dest is wave-uniform base + lane*16
DI void async16(unsigned short* lds, const unsigned short* g) {
    __builtin_amdgcn_global_load_lds(
        (const __attribute__((address_space(1))) void*)g,
        (__attribute__((address_space(3))) void*)lds,
        16, 0, 0);
}

// generic LDS pointer -> 32-bit LDS byte address (for asm ds_read)
DI unsigned ldsaddr(const void* p) {
    return (unsigned)(unsigned long long)
        (__attribute__((address_space(3))) const void*)p;
}

template <typename T> DI T cvt_out(float v);
template <> DI float cvt_out<float>(float v) { return v; }
template <> DI unsigned short cvt_out<unsigned short>(float v) { return f2bf(v); }

// 16 MFMAs: one quadrant (4 row-frags x 2 col-frags) x K=64 (2 k-steps).
template <int I0, int J0>
DI void mfma16(floatx4 (&acc)[8][4], const uint32x4 (&af)[4][2],
               const uint32x4 (&bf)[2][2]) {
#pragma unroll
    for (int s = 0; s < 2; s++)
#pragma unroll
        for (int i = 0; i < 4; i++)
#pragma unroll
            for (int j = 0; j < 2; j++)
                acc[I0 + i][J0 + j] = __builtin_amdgcn_mfma_f32_16x16x32_bf16(
                    __builtin_bit_cast(bf16x8, af[i][s]),
                    __builtin_bit_cast(bf16x8, bf[j][s]),
                    acc[I0 + i][J0 + j], 0, 0, 0);
}

// Stage one 128-row unit (2 x global_load_lds dwordx4 per wave).
#define STG_A(b, rb, kt) do { \
    async16(&As[b][(rb) * 64 + wofs], aS + (size_t)(rb) * K + (kt)); \
    async16(&As[b][((rb) + 64) * 64 + wofs], aS + (size_t)((rb) + 64) * K + (kt)); \
} while (0)
#define STG_B(b, rb, kt) do { \
    async16(&Bs[b][(rb) * 64 + wofs], bS + (size_t)(rb) * K + (kt)); \
    async16(&Bs[b][((rb) + 64) * 64 + wofs], bS + (size_t)((rb) + 64) * K + (kt)); \
} while (0)

// asm ds_read_b128: dst uint32x4 frag, 32-bit lds addr, literal byte offset.
// Opaque to compiler waitcnt insertion -> our counted lgkm waits govern.
#define DSR(dst, va, offs) \
    asm volatile("ds_read_b128 %0, %1 offset:" offs : "=&v"(dst) : "v"(va))

// A fragments: 4 row-frags x 2 k-slots; rows 16 apart = 2048 B apart.
#define LDA_LO(dst, va0, va1) do { \
    DSR(dst[0][0], va0, "0");     DSR(dst[0][1], va1, "0"); \
    DSR(dst[1][0], va0, "2048");  DSR(dst[1][1], va1, "2048"); \
    DSR(dst[2][0], va0, "4096");  DSR(dst[2][1], va1, "4096"); \
    DSR(dst[3][0], va0, "6144");  DSR(dst[3][1], va1, "6144"); \
} while (0)
#define LDA_HI(dst, va0, va1) do { \
    DSR(dst[0][0], va0, "16384"); DSR(dst[0][1], va1, "16384"); \
    DSR(dst[1][0], va0, "18432"); DSR(dst[1][1], va1, "18432"); \
    DSR(dst[2][0], va0, "20480"); DSR(dst[2][1], va1, "20480"); \
    DSR(dst[3][0], va0, "22528"); DSR(dst[3][1], va1, "22528"); \
} while (0)
// B fragments: 2 col-frags x 2 k-slots.
#define LDB_LO(dst, va0, va1) do { \
    DSR(dst[0][0], va0, "0");     DSR(dst[0][1], va1, "0"); \
    DSR(dst[1][0], va0, "2048");  DSR(dst[1][1], va1, "2048"); \
} while (0)
#define LDB_HI(dst, va0, va1) do { \
    DSR(dst[0][0], va0, "16384"); DSR(dst[0][1], va1, "16384"); \
    DSR(dst[1][0], va0, "18432"); DSR(dst[1][1], va1, "18432"); \
} while (0)

#define BARRIER do { __builtin_amdgcn_s_barrier(); \
    __builtin_amdgcn_sched_barrier(0); } while (0)
#define LGKM(n) do { asm volatile("s_waitcnt lgkmcnt(" #n ")" ::: "memory"); \
    __builtin_amdgcn_sched_barrier(0); } while (0)
#define GATE4 asm volatile("s_waitcnt vmcnt(4)" ::: "memory")
#define PRIO1 __builtin_amdgcn_s_setprio(1)
#define PRIO0 __builtin_amdgcn_s_setprio(0)

// ---------------------------------------------------------------------------
// C[M][N] = A[M][K] @ B[K][N] + bias, Bt = B^T given as [N][K] bf16.
// ---------------------------------------------------------------------------
template <int K, int N, int GX, typename OutT, bool RELU>
__global__ __launch_bounds__(512, 2)
void gemm256_bt(const unsigned short* __restrict__ A,   // [M][K] bf16
                const unsigned short* __restrict__ Bt,  // [N][K] bf16
                const float* __restrict__ bias,         // [N]
                OutT* __restrict__ C)                   // [M][N]
{
    constexpr int BK = 64;
    constexpr int NT = K / BK;      // 16 K-tiles
    constexpr int NP = NT / 2;      // 8 pair-iterations
    static_assert(NT % 2 == 0 && N % 256 == 0, "");

    __shared__ unsigned short As[2][256 * BK];   // 2 x 32 KB
    __shared__ unsigned short Bs[2][256 * BK];   // 2 x 32 KB

    const int tid  = threadIdx.x;
    const int wave = tid >> 6;
    const int lane = tid & 63;
    const int quad = lane >> 4;
    const int l16  = lane & 15;
    const int sw7  = l16 & 7;
    const int wm   = wave >> 2;     // 0..1 (M half)
    const int wn   = wave & 3;      // 0..3 (N quarter)

    // XCD swizzle (grids are multiples of 8 blocks)
    const int g   = blockIdx.x + GX * blockIdx.y;
    const int xcd = g & 7;
    const int t   = g >> 3;
    const int bx  = t % GX;
    const int by  = t / GX + (gridDim.y >> 3) * xcd;
    const int m0  = by * 256;
    const int n0  = bx * 256;

    // staging source: thread tid covers row (tid>>3) of a 64-row issue,
    // phys oct (tid&7) holds logical oct (tid&7)^(row&7)  (R4 swizzle)
    const int srow = tid >> 3;
    const int soct = ((tid & 7) ^ (srow & 7)) * 8;
    const unsigned short* aS = A  + (size_t)(m0 + srow) * K + soct;
    const unsigned short* bS = Bt + (size_t)(n0 + srow) * K + soct;
    const int wofs = wave * 512;    // wave's 8-row slice within an issue

    // frag-read LDS byte addresses: row stride 128B; logical oct o of row r
    // lives at phys oct o^(r&7); k-slot s uses oct (quad+4s)^sw7.
    const int aroB = (wm * 64 + l16) * 128;     // bytes
    const int broB = (wn * 32 + l16) * 128;
    const int s0B  = (quad ^ sw7) * 16;
    const int s1B  = ((quad + 4) ^ sw7) * 16;
    const unsigned vaA0_0 = ldsaddr(&As[0][0]) + aroB + s0B;
    const unsigned vaA0_1 = ldsaddr(&As[0][0]) + aroB + s1B;
    const unsigned vaA1_0 = ldsaddr(&As[1][0]) + aroB + s0B;
    const unsigned vaA1_1 = ldsaddr(&As[1][0]) + aroB + s1B;
    const unsigned vaB0_0 = ldsaddr(&Bs[0][0]) + broB + s0B;
    const unsigned vaB0_1 = ldsaddr(&Bs[0][0]) + broB + s1B;
    const unsigned vaB1_0 = ldsaddr(&Bs[1][0]) + broB + s0B;
    const unsigned vaB1_1 = ldsaddr(&Bs[1][0]) + broB + s1B;

    floatx4 acc[8][4];
    const floatx4 zero = {0.f, 0.f, 0.f, 0.f};
#pragma unroll
    for (int i = 0; i < 8; i++)
#pragma unroll
        for (int j = 0; j < 4; j++) acc[i][j] = zero;

    uint32x4 aL[4][2], aH[4][2], bL[2][2], bH[2][2];

    // Prologue: tile0 -> buf0, tile1 -> buf1 (16 loads); wait tile0 only;
    // read aL,bL of tile0 and drain once (loop entry: lgkm outstanding = 0).
    STG_A(0, 0, 0); STG_B(0, 0, 0); STG_B(0, 128, 0); STG_A(0, 128, 0);
    STG_A(1, 0, BK); STG_B(1, 0, BK); STG_B(1, 128, BK); STG_A(1, 128, BK);
    asm volatile("s_waitcnt vmcnt(8)" ::: "memory");
    BARRIER;
    LDA_LO(aL, vaA0_0, vaA0_1);
    LDB_LO(bL, vaB0_0, vaB0_1);
    LGKM(0);

#pragma unroll 1
    for (int it = 0; it < NP; ++it) {
        // tiles: E=2it (buf0), O=2it+1 (buf1); prefetch E'=2it+2, O'=2it+3
        const int kt2 = ((2 * it + 2) < NT ? (2 * it + 2) : (NT - 1)) * BK;
        const int kt3 = ((2 * it + 3) < NT ? (2 * it + 3) : (NT - 1)) * BK;

        // p1: MFMA Q1(E)=aL*bL | prefetch bH(E) | stage Alo(E')->buf0
        BARRIER;
        LDB_HI(bH, vaB0_0, vaB0_1);
        STG_A(0, 0, kt2);
        LGKM(4);
        PRIO1; mfma16<0, 0>(acc, aL, bL); PRIO0;

        // p2: MFMA Q2(E)=aL*bH | prefetch aH(E) | stage Blo(E')
        BARRIER;
        LDA_HI(aH, vaA0_0, vaA0_1);
        STG_B(0, 0, kt2);
        LGKM(8);
        PRIO1; mfma16<0, 2>(acc, aL, bH); PRIO0;

        // p3: gate tile O landed | MFMA Q3(E)=aH*bL | prefetch aL(O) | Bhi(E')
        GATE4;
        BARRIER;
        LDA_LO(aL, vaA1_0, vaA1_1);
        STG_B(0, 128, kt2);
        LGKM(8);
        PRIO1; mfma16<4, 0>(acc, aH, bL); PRIO0;

        // p4: MFMA Q4(E)=aH*bH | prefetch bL(O) | stage Ahi(E')
        BARRIER;
        LDB_LO(bL, vaB1_0, vaB1_1);
        STG_A(0, 128, kt2);
        LGKM(4);
        PRIO1; mfma16<4, 2>(acc, aH, bH); PRIO0;

        // p5: MFMA Q1(O)=aL*bL | prefetch bH(O) | stage Alo(O')->buf1
        BARRIER;
        LDB_HI(bH, vaB1_0, vaB1_1);
        STG_A(1, 0, kt3);
        LGKM(4);
        PRIO1; mfma16<0, 0>(acc, aL, bL); PRIO0;

        // p6: MFMA Q2(O)=aL*bH | prefetch aH(O) | stage Blo(O')
        BARRIER;
        LDA_HI(aH, vaA1_0, vaA1_1);
        STG_B(1, 0, kt3);
        LGKM(8);
        PRIO1; mfma16<0, 2>(acc, aL, bH); PRIO0;

        // p7: gate tile E' landed | MFMA Q3(O)=aH*bL | prefetch aL(E') | Bhi(O')
        GATE4;
        BARRIER;
        LDA_LO(aL, vaA0_0, vaA0_1);
        STG_B(1, 128, kt3);
        LGKM(8);
        PRIO1; mfma16<4, 0>(acc, aH, bL); PRIO0;

        // p8: MFMA Q4(O)=aH*bH | prefetch bL(E') | stage Ahi(O')
        BARRIER;
        LDB_LO(bL, vaB0_0, vaB0_1);
        STG_A(1, 128, kt3);
        LGKM(4);
        PRIO1; mfma16<4, 2>(acc, aH, bH); PRIO0;
    }
    // drain leftover loads/reads before epilogue/exit
    asm volatile("s_waitcnt vmcnt(0) lgkmcnt(0)" ::: "memory");
    __builtin_amdgcn_sched_barrier(0);

    // Epilogue (16x16x32 D layout: row = quad*4 + r, col = l16)
#pragma unroll
    for (int j = 0; j < 4; j++) {
        const int col = n0 + wn * 32 + (j & 1) * 16 + (j >> 1) * 128 + l16;
        const float bv = bias[col];
#pragma unroll
        for (int i = 0; i < 8; i++) {
            const int rb = m0 + wm * 64 + (i & 3) * 16 + (i >> 2) * 128 + quad * 4;
#pragma unroll
            for (int r = 0; r < 4; r++) {
                float v = acc[i][j][r] + bv;
                if (RELU) v = fmaxf(v, 0.f);
                C[(size_t)(rb + r) * N + col] = cvt_out<OutT>(v);
            }
        }
    }
}

#undef STG_A
#undef STG_B
#undef DSR
#undef LDA_LO
#undef LDA_HI
#undef LDB_LO
#undef LDB_HI
#undef BARRIER
#undef LGKM
#undef GATE4
#undef PRIO1
#undef PRIO0

// ---------------------------------------------------------------------------
// cast fp32 -> bf16, 4 elems/thread
__global__ void cast_f32_to_bf16(const float* __restrict__ src,
                                 unsigned short* __restrict__ dst, int n4) {
    int i = blockIdx.x * blockDim.x + threadIdx.x;
    if (i < n4) {
        float4 v = reinterpret_cast<const float4*>(src)[i];
        ushort4 o = { f2bf(v.x), f2bf(v.y), f2bf(v.z), f2bf(v.w) };
        reinterpret_cast<ushort4*>(dst)[i] = o;
    }
}

// 5x W[k][n] fp32 (1024x1024) -> Wt[n][k] bf16, z-indexed
struct WPack {
    const float* src[5];
    unsigned short* dst[5];
};
__global__ void transpose_cast_all(WPack p) {
    __shared__ float tile[32][33];
    const float* W = p.src[blockIdx.z];
    unsigned short* Wt = p.dst[blockIdx.z];
    const int n0 = blockIdx.x * 32, k0 = blockIdx.y * 32;
    const int tx = threadIdx.x, ty = threadIdx.y;  // 32 x 8
#pragma unroll
    for (int i = 0; i < 32; i += 8)
        tile[ty + i][tx] = W[(size_t)(k0 + ty + i) * 1024 + n0 + tx];
    __syncthreads();
#pragma unroll
    for (int i = 0; i < 32; i += 8)
        Wt[(size_t)(n0 + ty + i) * 1024 + k0 + tx] = f2bf(tile[tx][ty + i]);
}

__global__ void concat_bias(const float* __restrict__ bq,
                            const float* __restrict__ bk,
                            const float* __restrict__ bv,
                            float* __restrict__ dst) {
    int i = blockIdx.x * blockDim.x + threadIdx.x;  // 3072
    const float* s = (i < 1024) ? bq : ((i < 2048) ? bk : bv);
    dst[i] = s[i & 1023];
}

// ---------------------------------------------------------------------------
// Per-token attention over 8 heads. qkv row: [q(1024)|k(1024)|v(1024)] bf16.
// 4 tokens per block, ONE WAVE PER TOKEN. bf16 stays bf16 in LDS.
DI float dot8(unsigned a, unsigned b, float acc) {
    union { unsigned u; float f; } al, ah, bl, bh;
    al.u = a << 16; ah.u = a & 0xffff0000u;
    bl.u = b << 16; bh.u = b & 0xffff0000u;
    return acc + al.f * bl.f + ah.f * bh.f;
}

__global__ __launch_bounds__(256)
void attention_kernel(const unsigned short* __restrict__ qkv,  // [M][3072]
                      unsigned short* __restrict__ out_bf,     // [M][1024]
                      float* __restrict__ attn_w)              // [M][64]
{
    __shared__ unsigned short sqkv[4][3072];   // 24 KB
    __shared__ float sw[4][64];
    const int tid  = threadIdx.x;
    const int wave = tid >> 6;
    const int lane = tid & 63;
    const int m    = blockIdx.x * 4 + wave;    // this wave's token

    // Stage own token's qkv row: 384 uint4 chunks / 64 lanes = 6 per lane
    {
        const uint4* src = reinterpret_cast<const uint4*>(qkv + (size_t)m * 3072);
        uint4* dst = reinterpret_cast<uint4*>(&sqkv[wave][0]);
#pragma unroll
        for (int i = 0; i < 6; i++) dst[lane + 64 * i] = src[lane + 64 * i];
    }
    __syncthreads();

    // QK + softmax: lane = h*8 + t
    {
        const int h = lane >> 3, t = lane & 7;
        const uint2* q8 = reinterpret_cast<const uint2*>(&sqkv[wave][h * 128]);
        const uint2* k8 = reinterpret_cast<const uint2*>(&sqkv[wave][1024 + t * 128]);
        float dot = 0.f;
#pragma unroll
        for (int d = 0; d < 32; d++) {
            uint2 a = q8[d], b = k8[d];
            dot = dot8(a.x, b.x, dot);
            dot = dot8(a.y, b.y, dot);
        }
        float score = dot * 0.08838834764831843f;  // 1/sqrt(128)
        float mx = score;
#pragma unroll
        for (int o = 1; o < 8; o <<= 1) mx = fmaxf(mx, __shfl_xor(mx, o, 8));
        float e = __expf(score - mx);
        float sum = e;
#pragma unroll
        for (int o = 1; o < 8; o <<= 1) sum += __shfl_xor(sum, o, 8);
        float w = e / sum;
        sw[wave][lane] = w;
        attn_w[(size_t)m * 64 + lane] = w;     // [m][h][t], coalesced per wave
    }
    __syncthreads();

    // PV: lane owns output cols [lane*16, lane*16+16) = head h = lane>>3,
    // within-head dims d0..d0+15 with d0 = (lane&7)*16.  v is [t][d].
    {
        const int h  = lane >> 3;
        const int d0 = (lane & 7) * 16;        // within-head dim
        float acc[16];
#pragma unroll
        for (int i = 0; i < 16; i++) acc[i] = 0.f;
#pragma unroll
        for (int t = 0; t < 8; t++) {
            const float w = sw[wave][h * 8 + t];
            const uint4* v8 = reinterpret_cast<const uint4*>(
                &sqkv[wave][2048 + t * 128 + d0]);
            uint4 v0 = v8[0], v1 = v8[1];
            unsigned vv[8] = { v0.x, v0.y, v0.z, v0.w, v1.x, v1.y, v1.z, v1.w };
#pragma unroll
            for (int i = 0; i < 8; i++) {
                union { unsigned u; float f; } lo, hi;
                lo.u = vv[i] << 16; hi.u = vv[i] & 0xffff0000u;
                acc[i * 2]     += w * lo.f;
                acc[i * 2 + 1] += w * hi.f;
            }
        }
        unsigned o[8];
#pragma unroll
        for (int i = 0; i < 8; i++)
            o[i] = (unsigned)f2bf(acc[i * 2]) | ((unsigned)f2bf(acc[i * 2 + 1]) << 16);
        uint4* dst = reinterpret_cast<uint4*>(out_bf + (size_t)m * 1024 + lane * 16);
        dst[0] = make_uint4(o[0], o[1], o[2], o[3]);
        dst[1] = make_uint4(o[4], o[5], o[6], o[7]);
    }
}

// ---------------------------------------------------------------------------
extern "C" void kernel_launch(void* const* d_in, const int* in_sizes, int n_in,
                              void* d_out, int out_size, void* d_ws, size_t ws_size,
                              hipStream_t stream) {
    const float* x  = (const float*)d_in[0];
    const float* Wq = (const float*)d_in[1];
    const float* bq = (const float*)d_in[2];
    const float* Wk = (const float*)d_in[3];
    const float* bk = (const float*)d_in[4];
    const float* Wv = (const float*)d_in[5];
    const float* bv = (const float*)d_in[6];
    const float* W1 = (const float*)d_in[7];
    const float* b1 = (const float*)d_in[8];
    const float* W2 = (const float*)d_in[9];
    const float* b2 = (const float*)d_in[10];

    constexpr int D = 1024;
    constexpr int M = 4 * 4096;              // 16384 tokens
    constexpr size_t XN = (size_t)M * D;

    float* ff_out   = (float*)d_out;         // [M][1024]
    float* attn_out = (float*)d_out + XN;    // [M][64]

    char* ws = (char*)d_ws;
    size_t off = 0;
    auto alloc = [&](size_t bytes) -> char* {
        char* p = ws + off;
        off += (bytes + 255) & ~(size_t)255;
        return p;
    };
    unsigned short* Xbf   = (unsigned short*)alloc(XN * 2);
    unsigned short* Wtqkv = (unsigned short*)alloc((size_t)3 * D * D * 2);
    unsigned short* Wt1   = (unsigned short*)alloc((size_t)D * D * 2);
    unsigned short* Wt2   = (unsigned short*)alloc((size_t)D * D * 2);
    float*          bqkv  = (float*)alloc(3 * D * 4);
    unsigned short* outbf = (unsigned short*)alloc(XN * 2);
    unsigned short* hbf   = (unsigned short*)alloc(XN * 2);
    unsigned short* qkv   = (unsigned short*)alloc((size_t)M * 3 * D * 2);

    // prep
    cast_f32_to_bf16<<<(int)(XN / 4 / 256), 256, 0, stream>>>(x, Xbf, (int)(XN / 4));
    WPack p;
    p.src[0] = Wq; p.dst[0] = Wtqkv;
    p.src[1] = Wk; p.dst[1] = Wtqkv + (size_t)D * D;
    p.src[2] = Wv; p.dst[2] = Wtqkv + (size_t)2 * D * D;
    p.src[3] = W1; p.dst[3] = Wt1;
    p.src[4] = W2; p.dst[4] = Wt2;
    transpose_cast_all<<<dim3(32, 32, 5), dim3(32, 8), 0, stream>>>(p);
    concat_bias<<<12, 256, 0, stream>>>(bq, bk, bv, bqkv);

    // QKV projection + attention
    gemm256_bt<D, 3 * D, 12, unsigned short, false>
        <<<dim3(12, 64), 512, 0, stream>>>(Xbf, Wtqkv, bqkv, qkv);
    attention_kernel<<<M / 4, 256, 0, stream>>>(qkv, outbf, attn_out);

    // FFN
    gemm256_bt<D, D, 4, unsigned short, true>
        <<<dim3(4, 64), 512, 0, stream>>>(outbf, Wt1, b1, hbf);
    gemm256_bt<D, D, 4, float, false>
        <<<dim3(4, 64), 512, 0, stream>>>(hbf, Wt2, b2, ff_out);
}